// Round 5
// baseline (2603.009 us; speedup 1.0000x reference)
//
#include <hip/hip_runtime.h>

#define TSEQ 512

typedef unsigned short us8v __attribute__((ext_vector_type(8)));
typedef __bf16 bf16x8 __attribute__((ext_vector_type(8)));
typedef float f32x4 __attribute__((ext_vector_type(4)));
typedef unsigned u32x4 __attribute__((ext_vector_type(4)));

// ---- workspace layout (bytes) ----
#define OFF_FLAGS 0u           // [1024 widx][4 bg][32 hg] u32 = 512 KiB (write-once)
#define OFF_BIAS  524288u      // 2*2048 f32
#define OFF_X16   540672u      // x bf16 [512 t][64 b][64 d] = 4 MiB
#define OFF_W0    4734976u     // Wcat0 bf16 [2048][576]
#define OFF_W1    7094272u     // Wcat1 bf16 [2048][1024]
#define OFF_Y0    11288576u    // y0 bf16 [512 t][4 bg][16 b][512 h] = 32 MiB (write-once)
#define OFF_RING  44843008u    // h1 ring bf16 [2 par][4 bg][16 b][512 h] (reused -> bypass reads)

static __device__ __forceinline__ unsigned short f2bf(float f) {
    unsigned u = __builtin_bit_cast(unsigned, f);
    u += 0x7fffu + ((u >> 16) & 1u);            // RNE
    return (unsigned short)(u >> 16);
}
static __device__ __forceinline__ float sigmf(float x) { return 1.0f / (1.0f + __expf(-x)); }
static __device__ __forceinline__ float tanh_fast(float x) {
    float a = fabsf(x);
    float e = __expf(-2.0f * a);
    float t = (1.0f - e) / (1.0f + e);
    return copysignf(t, x);
}
static __device__ __forceinline__ f32x4 mfma16(us8v a, us8v b, f32x4 c) {
    return __builtin_amdgcn_mfma_f32_16x16x32_bf16(
        __builtin_bit_cast(bf16x8, a), __builtin_bit_cast(bf16x8, b), c, 0, 0, 0);
}

// ---------------- setup: fp32 -> bf16 conversions + concatenated weights ----------------
__global__ void setup_kernel(const float* __restrict__ x,
                             const float* __restrict__ wih0, const float* __restrict__ whh0,
                             const float* __restrict__ bih0, const float* __restrict__ bhh0,
                             const float* __restrict__ wih1, const float* __restrict__ whh1,
                             const float* __restrict__ bih1, const float* __restrict__ bhh1,
                             char* __restrict__ ws)
{
    unsigned idx = blockIdx.x * blockDim.x + threadIdx.x;
    unsigned stride = gridDim.x * blockDim.x;
    unsigned short* x16 = (unsigned short*)(ws + OFF_X16);
    unsigned short* w0  = (unsigned short*)(ws + OFF_W0);
    unsigned short* w1  = (unsigned short*)(ws + OFF_W1);
    float* bias = (float*)(ws + OFF_BIAS);
    const unsigned NX  = 64u*512u*64u;      // 2097152
    const unsigned NW0 = 2048u*576u;        // 1179648
    const unsigned NW1 = 2048u*1024u;       // 2097152
    const unsigned NT  = NX + NW0 + NW1 + 4096u;
    for (unsigned i = idx; i < NT; i += stride) {
        if (i < NX) {
            // transpose to [t][b][d]
            unsigned d = i & 63u, b = (i >> 6) & 63u, t = i >> 12;
            x16[i] = f2bf(x[((b << 9) + t) * 64u + d]);
        } else if (i < NX + NW0) {
            unsigned k = i - NX; unsigned r = k / 576u, c = k % 576u;
            float v = (c < 64u) ? wih0[r*64u + c] : whh0[r*512u + (c - 64u)];
            w0[k] = f2bf(v);
        } else if (i < NX + NW0 + NW1) {
            unsigned k = i - NX - NW0; unsigned r = k >> 10, c = k & 1023u;
            float v = (c < 512u) ? wih1[(r<<9) + c] : whh1[(r<<9) + (c - 512u)];
            w1[k] = f2bf(v);
        } else {
            unsigned k = i - NX - NW0 - NW1;   // 0..4095
            float v = (k < 2048u) ? (bih0[k] + bhh0[k]) : (bih1[k-2048u] + bhh1[k-2048u]);
            bias[k] = v;
        }
    }
}

// ---------------- persistent recurrence kernel ----------------
// 128 blocks = 4 bg x 32 hg. B-operand fragments load global->register
// directly (the [b][k] row-major layout IS fragment-shaped: 16B per (lane,kt)).
// LDS only for the cross-wave gate reduction (gsum). Sync through coherent
// memory-side L3: sc0sc1 write-through h/flag stores, sc0sc1 polls.
__launch_bounds__(256, 1)
__global__ void lstm_persist(char* __restrict__ ws)
{
    const int tid  = threadIdx.x;
    const int kq   = tid >> 6;      // wave = K-quarter
    const int lane = tid & 63;
    const int l15  = lane & 15;     // B-frag batch row / D col
    const int lhi  = lane >> 4;     // k-sub / D row-group
    const int bg   = blockIdx.x & 3;
    const int hg   = blockIdx.x >> 2;

    unsigned* flags   = (unsigned*)(ws + OFF_FLAGS);
    const float* bias = (const float*)(ws + OFF_BIAS);
    const char*  x16  = ws + OFF_X16;
    char* y0   = ws + OFF_Y0;
    char* ring = ws + OFF_RING;

    __shared__ float gsum[64 * 68];   // [row 0..63][kq 0..3 *17 + b]  (2-way max banks)
    __shared__ float bias_l[64];

    if (tid < 64) bias_l[tid] = bias[(tid >> 4)*512 + hg*16 + (tid & 15)];

    // per-thread cell state: thread owns (b = tid>>4, p = tid&15)
    float cst = 0.0f;

    // A fragments: A[m][kk], m = gate, kk = local k-tile of this wave
    us8v A[4][8];
    {
        const char* w0p = ws + OFF_W0;
        #pragma unroll
        for (int m = 0; m < 4; ++m) {
            const char* base = w0p + (size_t)(m*512 + hg*16 + l15)*1152 + lhi*16;
            #pragma unroll
            for (int kk = 0; kk < 4; ++kk)
                A[m][kk] = *(const us8v*)(base + (2 + kq*4 + kk)*64);   // h k-tiles
            if (kq < 2) A[m][4] = *(const us8v*)(base + kq*64);         // x k-tiles
        }
    }
    __syncthreads();

    // per-lane byte offset of this lane's fragment within a [16 b][512 h] slot
    const int fragoff = l15*1024 + kq*256 + lhi*16;

#define POLL(WIDX) do {                                                              \
        const unsigned* fp_ = flags + (size_t)(WIDX)*128 + bg*32 + (lane & 31);      \
        unsigned fv_;                                                                \
        do {                                                                         \
            asm volatile("global_load_dword %0, %1, off sc0 sc1\n\ts_waitcnt vmcnt(0)" \
                         : "=v"(fv_) : "v"(fp_) : "memory");                         \
        } while (!__all(fv_ != 0u));                                                 \
    } while (0)

#define ACTIVATION_STORE(DSTBASE) do {                                               \
        int b_ = tid >> 4, p_ = tid & 15;                                            \
        float g4_[4];                                                                \
        _Pragma("unroll")                                                            \
        for (int g = 0; g < 4; ++g) {                                                \
            float s_ = bias_l[g*16 + p_];                                            \
            _Pragma("unroll")                                                        \
            for (int kk = 0; kk < 4; ++kk) s_ += gsum[(g*16 + p_)*68 + kk*17 + b_];  \
            g4_[g] = s_;                                                             \
        }                                                                            \
        float iv_ = sigmf(g4_[0]), fv_ = sigmf(g4_[1]);                              \
        float gv_ = tanh_fast(g4_[2]), ov_ = sigmf(g4_[3]);                          \
        cst = fv_*cst + iv_*gv_;                                                     \
        float h_ = ov_ * tanh_fast(cst);                                             \
        unsigned hv_ = f2bf(h_);                                                     \
        unsigned pk_ = (hv_ & 0xffffu) | (((unsigned)__shfl_xor((int)hv_, 1)) << 16);\
        if (!(p_ & 1)) {                                                             \
            const char* dst_ = (DSTBASE) + b_*1024 + (hg*16 + p_)*2;                 \
            asm volatile("global_store_dword %0, %1, off sc0 sc1"                    \
                         :: "v"(dst_), "v"(pk_) : "memory");                         \
        }                                                                            \
    } while (0)

    // ================= layer 0 : K = 576 = [x_t(64) | h0(512)] =================
    for (int t = 0; t < TSEQ; ++t) {
        us8v xf = {};
        if (kq < 2)   // x fragment (cached; completes during poll)
            xf = *(const us8v*)(x16 + (size_t)t*8192 + (bg*16 + l15)*128 + kq*64 + lhi*16);

        f32x4 acc[4] = {{0.f,0.f,0.f,0.f},{0.f,0.f,0.f,0.f},{0.f,0.f,0.f,0.f},{0.f,0.f,0.f,0.f}};
        if (t > 0) {
            POLL(t-1);
            // h fragments direct from y0[t-1] (write-once, first touch after flag -> cached)
            const char* hb = y0 + ((size_t)(t-1)*4 + bg)*16384 + fragoff;
            us8v hf0 = *(const us8v*)(hb);
            us8v hf1 = *(const us8v*)(hb + 64);
            us8v hf2 = *(const us8v*)(hb + 128);
            us8v hf3 = *(const us8v*)(hb + 192);
            if (kq < 2) {
                #pragma unroll
                for (int m = 0; m < 4; ++m) acc[m] = mfma16(A[m][4], xf, acc[m]);
            }
            #pragma unroll
            for (int m = 0; m < 4; ++m) acc[m] = mfma16(A[m][0], hf0, acc[m]);
            #pragma unroll
            for (int m = 0; m < 4; ++m) acc[m] = mfma16(A[m][1], hf1, acc[m]);
            #pragma unroll
            for (int m = 0; m < 4; ++m) acc[m] = mfma16(A[m][2], hf2, acc[m]);
            #pragma unroll
            for (int m = 0; m < 4; ++m) acc[m] = mfma16(A[m][3], hf3, acc[m]);
        } else if (kq < 2) {
            #pragma unroll
            for (int m = 0; m < 4; ++m) acc[m] = mfma16(A[m][4], xf, acc[m]);
        }
        #pragma unroll
        for (int m = 0; m < 4; ++m) {
            #pragma unroll
            for (int q = 0; q < 4; ++q)
                gsum[(m*16 + lhi*4 + q)*68 + kq*17 + l15] = acc[m][q];
        }
        __syncthreads();
        ACTIVATION_STORE(y0 + ((size_t)t*4 + bg)*16384);
        asm volatile("s_waitcnt vmcnt(0)" ::: "memory");   // h visible at L3
        __syncthreads();
        if (tid == 0) {
            unsigned one = 1;
            const unsigned* fq = flags + (size_t)t*128 + bg*32 + hg;
            asm volatile("global_store_dword %0, %1, off sc0 sc1"
                         :: "v"(fq), "v"(one) : "memory");
        }
    }

    // ---- reload A + bias for layer 1 (K = 1024 = [y0(512) | h1(512)]) ----
    {
        const char* w1p = ws + OFF_W1;
        #pragma unroll
        for (int m = 0; m < 4; ++m) {
            const char* base = w1p + (size_t)(m*512 + hg*16 + l15)*2048 + lhi*16;
            #pragma unroll
            for (int kk = 0; kk < 4; ++kk) {
                A[m][kk]     = *(const us8v*)(base + (kq*4 + kk)*64);        // y0 k-tiles
                A[m][kk + 4] = *(const us8v*)(base + (16 + kq*4 + kk)*64);   // h  k-tiles
            }
        }
    }
    if (tid < 64) bias_l[tid] = bias[2048 + (tid >> 4)*512 + hg*16 + (tid & 15)];
    __syncthreads();
    // cst carries over: layer1 initial c = layer0 final c (reference quirk)

    for (int t = 0; t < TSEQ; ++t) {
        // y0[t] fragments (confirmed long ago; cached). Issue BEFORE poll; the
        // poll's vmcnt(0) absorbs their latency.
        const char* yb = y0 + ((size_t)t*4 + bg)*16384 + fragoff;
        us8v yf0 = *(const us8v*)(yb);
        us8v yf1 = *(const us8v*)(yb + 64);
        us8v yf2 = *(const us8v*)(yb + 128);
        us8v yf3 = *(const us8v*)(yb + 192);

        POLL(t == 0 ? 511 : 511 + t);

        // h1 fragments: ring is reused -> bypass caches (sc0 sc1). Issue now,
        // hide latency under the y0-half MFMAs.
        const char* s1 = ((t == 0) ? (y0 + ((size_t)511*4 + bg)*16384)
                                   : (ring + ((size_t)((t-1) & 1)*4 + bg)*16384)) + fragoff;
        u32x4 r0, r1, r2, r3;
        {
            const char* a0 = s1;
            const char* a1 = s1 + 64;
            const char* a2 = s1 + 128;
            const char* a3 = s1 + 192;
            asm volatile("global_load_dwordx4 %0, %1, off sc0 sc1"
                         : "=v"(r0) : "v"(a0) : "memory");
            asm volatile("global_load_dwordx4 %0, %1, off sc0 sc1"
                         : "=v"(r1) : "v"(a1) : "memory");
            asm volatile("global_load_dwordx4 %0, %1, off sc0 sc1"
                         : "=v"(r2) : "v"(a2) : "memory");
            asm volatile("global_load_dwordx4 %0, %1, off sc0 sc1"
                         : "=v"(r3) : "v"(a3) : "memory");
        }

        f32x4 acc[4] = {{0.f,0.f,0.f,0.f},{0.f,0.f,0.f,0.f},{0.f,0.f,0.f,0.f},{0.f,0.f,0.f,0.f}};
        #pragma unroll
        for (int m = 0; m < 4; ++m) acc[m] = mfma16(A[m][0], yf0, acc[m]);
        #pragma unroll
        for (int m = 0; m < 4; ++m) acc[m] = mfma16(A[m][1], yf1, acc[m]);
        #pragma unroll
        for (int m = 0; m < 4; ++m) acc[m] = mfma16(A[m][2], yf2, acc[m]);
        #pragma unroll
        for (int m = 0; m < 4; ++m) acc[m] = mfma16(A[m][3], yf3, acc[m]);

        // fence: tie the ring registers to the waitcnt so MFMAs below can't hoist
        asm volatile("s_waitcnt vmcnt(0)"
                     : "+v"(r0), "+v"(r1), "+v"(r2), "+v"(r3) :: "memory");
        __builtin_amdgcn_sched_barrier(0);

        #pragma unroll
        for (int m = 0; m < 4; ++m) acc[m] = mfma16(A[m][4], __builtin_bit_cast(us8v, r0), acc[m]);
        #pragma unroll
        for (int m = 0; m < 4; ++m) acc[m] = mfma16(A[m][5], __builtin_bit_cast(us8v, r1), acc[m]);
        #pragma unroll
        for (int m = 0; m < 4; ++m) acc[m] = mfma16(A[m][6], __builtin_bit_cast(us8v, r2), acc[m]);
        #pragma unroll
        for (int m = 0; m < 4; ++m) acc[m] = mfma16(A[m][7], __builtin_bit_cast(us8v, r3), acc[m]);

        #pragma unroll
        for (int m = 0; m < 4; ++m) {
            #pragma unroll
            for (int q = 0; q < 4; ++q)
                gsum[(m*16 + lhi*4 + q)*68 + kq*17 + l15] = acc[m][q];
        }
        __syncthreads();
        ACTIVATION_STORE(ring + ((size_t)(t & 1)*4 + bg)*16384);
        asm volatile("s_waitcnt vmcnt(0)" ::: "memory");
        __syncthreads();
        if (tid == 0) {
            unsigned one = 1;
            const unsigned* fq = flags + (size_t)(512 + t)*128 + bg*32 + hg;
            asm volatile("global_store_dword %0, %1, off sc0 sc1"
                         :: "v"(fq), "v"(one) : "memory");
        }
    }
#undef POLL
#undef ACTIVATION_STORE
}

// ---------------- final projection: out = h1_final @ lin_w.T + lin_b ----------------
__global__ void final_linear(const char* __restrict__ ws,
                             const float* __restrict__ linw, const float* __restrict__ linb,
                             float* __restrict__ out)
{
    __shared__ float hrow[512];
    int b = blockIdx.x;        // global batch 0..63
    int o = threadIdx.x;       // 64 outputs
    int bg = b >> 4, bl = b & 15;
    // t=511 -> ring parity 1
    const char* src = ws + OFF_RING + ((size_t)1*4 + bg)*16384 + (size_t)bl*1024;
    {
        us8v v = *(const us8v*)(src + o*16);
        #pragma unroll
        for (int p = 0; p < 8; ++p)
            hrow[o*8+p] = __builtin_bit_cast(float, ((unsigned)v[p]) << 16);
    }
    __syncthreads();
    float acc = linb[o];
    const float* wrow = linw + o*512;
    #pragma unroll 8
    for (int k = 0; k < 512; ++k) acc += hrow[k] * wrow[k];
    out[b*64 + o] = acc;
}

extern "C" void kernel_launch(void* const* d_in, const int* in_sizes, int n_in,
                              void* d_out, int out_size, void* d_ws, size_t ws_size,
                              hipStream_t stream)
{
    const float* x    = (const float*)d_in[0];
    const float* wih0 = (const float*)d_in[1];
    const float* whh0 = (const float*)d_in[2];
    const float* bih0 = (const float*)d_in[3];
    const float* bhh0 = (const float*)d_in[4];
    const float* wih1 = (const float*)d_in[5];
    const float* whh1 = (const float*)d_in[6];
    const float* bih1 = (const float*)d_in[7];
    const float* bhh1 = (const float*)d_in[8];
    const float* linw = (const float*)d_in[9];
    const float* linb = (const float*)d_in[10];
    char* ws = (char*)d_ws;

    // zero step flags (visible to lstm_persist via dispatch-boundary ordering)
    (void)hipMemsetAsync(ws + OFF_FLAGS, 0, 524288, stream);
    hipLaunchKernelGGL(setup_kernel, dim3(1024), dim3(256), 0, stream,
                       x, wih0, whh0, bih0, bhh0, wih1, whh1, bih1, bhh1, ws);
    hipLaunchKernelGGL(lstm_persist, dim3(128), dim3(256), 0, stream, ws);
    hipLaunchKernelGGL(final_linear, dim3(64), dim3(64), 0, stream,
                       ws, linw, linb, (float*)d_out);
}

// Round 6
// 2332.463 us; speedup vs baseline: 1.1160x; 1.1160x over previous
//
#include <hip/hip_runtime.h>

#define TSEQ 512

typedef unsigned short us8v __attribute__((ext_vector_type(8)));
typedef __bf16 bf16x8 __attribute__((ext_vector_type(8)));
typedef float f32x4 __attribute__((ext_vector_type(4)));
typedef unsigned u32x4 __attribute__((ext_vector_type(4)));

// ---- workspace layout (bytes) ----
#define OFF_FLAGS 0u           // [4 bg][32 hg] epoch u32 @ 128B stride = 16 KiB
#define OFF_BIAS  16384u       // 2*2048 f32
#define OFF_X16   32768u       // x bf16 [512 t][64 b][64 d] = 4 MiB
#define OFF_W0    4227072u     // Wcat0 bf16 [2048][576]
#define OFF_W1    6586368u     // Wcat1 bf16 [2048][1024]
#define OFF_Y0    10780672u    // y0 xch bf16 [512 t][4 bg][32 hg][16 b][16 p] = 32 MiB
#define OFF_RING  44335104u    // h1 ring bf16 [2 par][4 bg][32 hg][16 b][16 p] = 128 KiB

static __device__ __forceinline__ unsigned short f2bf(float f) {
    unsigned u = __builtin_bit_cast(unsigned, f);
    u += 0x7fffu + ((u >> 16) & 1u);            // RNE
    return (unsigned short)(u >> 16);
}
static __device__ __forceinline__ float sigmf(float x) { return 1.0f / (1.0f + __expf(-x)); }
static __device__ __forceinline__ float tanh_fast(float x) {
    float a = fabsf(x);
    float e = __expf(-2.0f * a);
    float t = (1.0f - e) / (1.0f + e);
    return copysignf(t, x);
}
static __device__ __forceinline__ f32x4 mfma16(us8v a, us8v b, f32x4 c) {
    return __builtin_amdgcn_mfma_f32_16x16x32_bf16(
        __builtin_bit_cast(bf16x8, a), __builtin_bit_cast(bf16x8, b), c, 0, 0, 0);
}
static __device__ __forceinline__ us8v asb(u32x4 v) { return __builtin_bit_cast(us8v, v); }

// ---------------- setup: fp32 -> bf16 conversions + concatenated weights ----------------
__global__ void setup_kernel(const float* __restrict__ x,
                             const float* __restrict__ wih0, const float* __restrict__ whh0,
                             const float* __restrict__ bih0, const float* __restrict__ bhh0,
                             const float* __restrict__ wih1, const float* __restrict__ whh1,
                             const float* __restrict__ bih1, const float* __restrict__ bhh1,
                             char* __restrict__ ws)
{
    unsigned idx = blockIdx.x * blockDim.x + threadIdx.x;
    unsigned stride = gridDim.x * blockDim.x;
    unsigned short* x16 = (unsigned short*)(ws + OFF_X16);
    unsigned short* w0  = (unsigned short*)(ws + OFF_W0);
    unsigned short* w1  = (unsigned short*)(ws + OFF_W1);
    float* bias = (float*)(ws + OFF_BIAS);
    const unsigned NX  = 64u*512u*64u;      // 2097152
    const unsigned NW0 = 2048u*576u;        // 1179648
    const unsigned NW1 = 2048u*1024u;       // 2097152
    const unsigned NT  = NX + NW0 + NW1 + 4096u;
    for (unsigned i = idx; i < NT; i += stride) {
        if (i < NX) {
            // transpose to [t][b][d]
            unsigned d = i & 63u, b = (i >> 6) & 63u, t = i >> 12;
            x16[i] = f2bf(x[((b << 9) + t) * 64u + d]);
        } else if (i < NX + NW0) {
            unsigned k = i - NX; unsigned r = k / 576u, c = k % 576u;
            float v = (c < 64u) ? wih0[r*64u + c] : whh0[r*512u + (c - 64u)];
            w0[k] = f2bf(v);
        } else if (i < NX + NW0 + NW1) {
            unsigned k = i - NX - NW0; unsigned r = k >> 10, c = k & 1023u;
            float v = (c < 512u) ? wih1[(r<<9) + c] : whh1[(r<<9) + (c - 512u)];
            w1[k] = f2bf(v);
        } else {
            unsigned k = i - NX - NW0 - NW1;   // 0..4095
            float v = (k < 2048u) ? (bih0[k] + bhh0[k]) : (bih1[k-2048u] + bhh1[k-2048u]);
            bias[k] = v;
        }
    }
}

// ---------------- persistent recurrence kernel ----------------
// 128 blocks = 4 bg x 32 hg. Monotone epoch flag per block (128B-spread),
// 2-deep pipelined poll, block-major 512B payload (one 128B line per wave),
// one barrier per step + per-wave ack + LDS wave-counter flag release.
// ALL global loads inside the loops are inline asm (stale-poll-safe waits).
__launch_bounds__(256, 1)
__global__ void lstm_persist(char* __restrict__ ws)
{
    const int tid  = threadIdx.x;
    const int kq   = tid >> 6;      // wave = K-quarter
    const int lane = tid & 63;
    const int l15  = lane & 15;     // B-frag batch row / D col
    const int lhi  = lane >> 4;     // k-sub / D row-group
    const int bg   = blockIdx.x & 3;
    const int hg   = blockIdx.x >> 2;

    const float* bias = (const float*)(ws + OFF_BIAS);
    const char*  x16  = ws + OFF_X16;
    char* y0   = ws + OFF_Y0;
    char* ring = ws + OFF_RING;
    const char* flagbase = ws + OFF_FLAGS + bg*4096;   // 32 slots @128B
    const char* fq       = flagbase + hg*128;          // our slot

    __shared__ __align__(16) char arena[86016];        // >80KB -> 1 block/CU
    float* gsum       = (float*)arena;                 // [2 par][64 rows][4*17] = 34816 B
    float* bias_l     = (float*)(arena + 34816);       // 64 f32
    unsigned* wcnt    = (unsigned*)(arena + 35072);    // [2] wave-done counters

    if (tid == 0) { wcnt[0] = 0u; wcnt[1] = 0u; }
    if (tid < 64) bias_l[tid] = bias[(tid >> 4)*512 + hg*16 + (tid & 15)];

    float cst = 0.0f;   // cell state: thread owns (b = tid>>4, p = tid&15)

    // A fragments: A[m][kk], m = gate, kk = local k-tile of this wave
    us8v A[4][8];
    {
        const char* w0p = ws + OFF_W0;
        #pragma unroll
        for (int m = 0; m < 4; ++m) {
            const char* base = w0p + (size_t)(m*512 + hg*16 + l15)*1152 + lhi*16;
            #pragma unroll
            for (int kk = 0; kk < 4; ++kk)
                A[m][kk] = *(const us8v*)(base + (2 + kq*4 + kk)*64);   // h k-tiles
            if (kq < 2) A[m][4] = *(const us8v*)(base + kq*64);         // x k-tiles
        }
    }
    __syncthreads();

    // lane's fragment byte offset inside a [32 hg][16 b][16 p] (16KB) xch slot:
    // k-tile kt (32 k) -> hg' = kt*2 + (lhi>>1); addr = hg'*512 + l15*32 + (lhi&1)*16
    const int base_off = kq*4096 + (lhi >> 1)*512 + l15*32 + (lhi & 1)*16;   // kk stride 1024

    unsigned pf0 = 0, pf1 = 0;   // poll ping-pong regs (live across straggler window)

#define POLL(EP) do {                                                            \
        unsigned ep_ = (EP);                                                     \
        const char* fp_ = flagbase + ((lane & 31) << 7);                         \
        asm volatile(                                                            \
            "global_load_dword %0, %2, off sc0 sc1\n\t"                          \
            "global_load_dword %1, %2, off sc0 sc1\n\t"                          \
            "1:\n\t"                                                             \
            "s_waitcnt vmcnt(1)\n\t"                                             \
            "v_cmp_lt_u32 vcc, %0, %3\n\t"                                       \
            "s_cbranch_vccz 2f\n\t"                                              \
            "global_load_dword %0, %2, off sc0 sc1\n\t"                          \
            "s_waitcnt vmcnt(1)\n\t"                                             \
            "v_cmp_lt_u32 vcc, %1, %3\n\t"                                       \
            "s_cbranch_vccz 2f\n\t"                                              \
            "global_load_dword %1, %2, off sc0 sc1\n\t"                          \
            "s_branch 1b\n\t"                                                    \
            "2:\n\t"                                                             \
            : "+v"(pf0), "+v"(pf1) : "v"(fp_), "s"(ep_) : "vcc", "memory");      \
    } while (0)

#define GSUM_WRITE(PAR) do {                                                     \
        float* gs_ = gsum + (PAR)*4352;                                          \
        _Pragma("unroll")                                                        \
        for (int m = 0; m < 4; ++m) {                                            \
            _Pragma("unroll")                                                    \
            for (int q = 0; q < 4; ++q)                                          \
                gs_[(m*16 + lhi*4 + q)*68 + kq*17 + l15] = acc[m][q];            \
        }                                                                        \
    } while (0)

#define ACT_TAIL(SLICE, EPOCH, PAR) do {                                         \
        int b_ = tid >> 4, p_ = tid & 15;                                        \
        const float* gsr_ = gsum + (PAR)*4352;                                   \
        float g4_[4];                                                            \
        _Pragma("unroll")                                                        \
        for (int g = 0; g < 4; ++g) {                                            \
            float s_ = bias_l[g*16 + p_];                                        \
            _Pragma("unroll")                                                    \
            for (int kk = 0; kk < 4; ++kk) s_ += gsr_[(g*16 + p_)*68 + kk*17 + b_]; \
            g4_[g] = s_;                                                         \
        }                                                                        \
        float iv_ = sigmf(g4_[0]), fv_ = sigmf(g4_[1]);                          \
        float gv_ = tanh_fast(g4_[2]), ov_ = sigmf(g4_[3]);                      \
        cst = fv_*cst + iv_*gv_;                                                 \
        float h_ = ov_ * tanh_fast(cst);                                         \
        unsigned hv_ = f2bf(h_);                                                 \
        unsigned pk_ = (hv_ & 0xffffu) | (((unsigned)__shfl_xor((int)hv_, 1)) << 16); \
        if (!(p_ & 1)) {                                                         \
            const char* dst_ = (SLICE) + b_*32 + p_*2;                           \
            asm volatile("global_store_dword %0, %1, off sc0 sc1"                \
                         :: "v"(dst_), "v"(pk_) : "memory");                     \
        }                                                                        \
        asm volatile("s_waitcnt vmcnt(0)" ::: "memory");                         \
        if (lane == 0) {                                                         \
            unsigned prev_ = __hip_atomic_fetch_add(&wcnt[PAR], 1u,              \
                                __ATOMIC_RELAXED, __HIP_MEMORY_SCOPE_WORKGROUP); \
            if (prev_ == 3u) {                                                   \
                __hip_atomic_store(&wcnt[PAR], 0u,                               \
                                __ATOMIC_RELAXED, __HIP_MEMORY_SCOPE_WORKGROUP); \
                unsigned ep_ = (EPOCH);                                          \
                asm volatile("global_store_dword %0, %1, off sc0 sc1"            \
                             :: "v"(fq), "v"(ep_) : "memory");                   \
            }                                                                    \
        }                                                                        \
    } while (0)

    // ================= layer 0 : K = 576 = [x_t(64) | h0(512)] =================
    for (int t = 0; t < TSEQ; ++t) {
        u32x4 xr;
        const bool havex = (kq < 2);
        if (havex) {   // x fragment, issued before poll (plain cached, retired by poll exit)
            const char* xaddr = x16 + (size_t)t*8192 + (bg*16 + l15)*128 + kq*64 + lhi*16;
            asm volatile("global_load_dwordx4 %0, %1, off" : "=v"(xr) : "v"(xaddr) : "memory");
        }
        f32x4 acc[4] = {{0.f,0.f,0.f,0.f},{0.f,0.f,0.f,0.f},{0.f,0.f,0.f,0.f},{0.f,0.f,0.f,0.f}};
        if (t > 0) {
            POLL((unsigned)t);
            const char* hb = y0 + ((size_t)(t-1)*4 + bg)*16384 + base_off;
            u32x4 h0, h1, h2, h3;
            asm volatile("global_load_dwordx4 %0, %4, off\n\t"
                         "global_load_dwordx4 %1, %5, off\n\t"
                         "global_load_dwordx4 %2, %6, off\n\t"
                         "global_load_dwordx4 %3, %7, off"
                         : "=&v"(h0), "=&v"(h1), "=&v"(h2), "=&v"(h3)
                         : "v"(hb), "v"(hb+1024), "v"(hb+2048), "v"(hb+3072) : "memory");
            if (havex) {
                asm volatile("" : "+v"(xr));    // ordered after poll; xr retired at poll exit
                #pragma unroll
                for (int m = 0; m < 4; ++m) acc[m] = mfma16(A[m][4], asb(xr), acc[m]);
            }
            asm volatile("s_waitcnt vmcnt(0)"
                         : "+v"(h0), "+v"(h1), "+v"(h2), "+v"(h3) :: "memory");
            asm volatile("" :: "v"(pf0), "v"(pf1));   // poll stragglers landed; release
            #pragma unroll
            for (int m = 0; m < 4; ++m) acc[m] = mfma16(A[m][0], asb(h0), acc[m]);
            #pragma unroll
            for (int m = 0; m < 4; ++m) acc[m] = mfma16(A[m][1], asb(h1), acc[m]);
            #pragma unroll
            for (int m = 0; m < 4; ++m) acc[m] = mfma16(A[m][2], asb(h2), acc[m]);
            #pragma unroll
            for (int m = 0; m < 4; ++m) acc[m] = mfma16(A[m][3], asb(h3), acc[m]);
        } else if (havex) {
            asm volatile("s_waitcnt vmcnt(0)" : "+v"(xr) :: "memory");
            #pragma unroll
            for (int m = 0; m < 4; ++m) acc[m] = mfma16(A[m][4], asb(xr), acc[m]);
        }
        GSUM_WRITE(t & 1);
        __syncthreads();
        ACT_TAIL(y0 + ((size_t)t*4 + bg)*16384 + hg*512, (unsigned)(t + 1), (t & 1));
    }

    // ---- reload A + bias for layer 1 (K = 1024 = [y0(512) | h1(512)]) ----
    {
        const char* w1p = ws + OFF_W1;
        #pragma unroll
        for (int m = 0; m < 4; ++m) {
            const char* base = w1p + (size_t)(m*512 + hg*16 + l15)*2048 + lhi*16;
            #pragma unroll
            for (int kk = 0; kk < 4; ++kk) {
                A[m][kk]     = *(const us8v*)(base + (kq*4 + kk)*64);        // y0 k-tiles
                A[m][kk + 4] = *(const us8v*)(base + (16 + kq*4 + kk)*64);   // h  k-tiles
            }
        }
    }
    if (tid < 64) bias_l[tid] = bias[2048 + (tid >> 4)*512 + hg*16 + (tid & 15)];
    __syncthreads();
    // cst carries over: layer1 initial c = layer0 final c (reference quirk)

    for (int t = 0; t < TSEQ; ++t) {
        // y0[t] fragments: issued before poll; retired by the poll's vmcnt waits.
        const char* yb = y0 + ((size_t)t*4 + bg)*16384 + base_off;
        u32x4 yr0, yr1, yr2, yr3;
        asm volatile("global_load_dwordx4 %0, %4, off\n\t"
                     "global_load_dwordx4 %1, %5, off\n\t"
                     "global_load_dwordx4 %2, %6, off\n\t"
                     "global_load_dwordx4 %3, %7, off"
                     : "=&v"(yr0), "=&v"(yr1), "=&v"(yr2), "=&v"(yr3)
                     : "v"(yb), "v"(yb+1024), "v"(yb+2048), "v"(yb+3072) : "memory");

        POLL((unsigned)(512 + t));

        // h1 fragments (ring reused -> bypass caches); latency hides under y0 MFMAs
        const char* rb = ((t == 0) ? (y0 + ((size_t)511*4 + bg)*16384)
                                   : (ring + ((size_t)((t-1) & 1)*4 + bg)*16384)) + base_off;
        u32x4 r0, r1, r2, r3;
        asm volatile("global_load_dwordx4 %0, %4, off sc0 sc1\n\t"
                     "global_load_dwordx4 %1, %5, off sc0 sc1\n\t"
                     "global_load_dwordx4 %2, %6, off sc0 sc1\n\t"
                     "global_load_dwordx4 %3, %7, off sc0 sc1"
                     : "=&v"(r0), "=&v"(r1), "=&v"(r2), "=&v"(r3)
                     : "v"(rb), "v"(rb+1024), "v"(rb+2048), "v"(rb+3072) : "memory");

        asm volatile("" : "+v"(yr0), "+v"(yr1), "+v"(yr2), "+v"(yr3));  // after poll; retired
        f32x4 acc[4] = {{0.f,0.f,0.f,0.f},{0.f,0.f,0.f,0.f},{0.f,0.f,0.f,0.f},{0.f,0.f,0.f,0.f}};
        #pragma unroll
        for (int m = 0; m < 4; ++m) acc[m] = mfma16(A[m][0], asb(yr0), acc[m]);
        #pragma unroll
        for (int m = 0; m < 4; ++m) acc[m] = mfma16(A[m][1], asb(yr1), acc[m]);
        #pragma unroll
        for (int m = 0; m < 4; ++m) acc[m] = mfma16(A[m][2], asb(yr2), acc[m]);
        #pragma unroll
        for (int m = 0; m < 4; ++m) acc[m] = mfma16(A[m][3], asb(yr3), acc[m]);

        asm volatile("s_waitcnt vmcnt(0)"
                     : "+v"(r0), "+v"(r1), "+v"(r2), "+v"(r3) :: "memory");
        asm volatile("" :: "v"(pf0), "v"(pf1));
        #pragma unroll
        for (int m = 0; m < 4; ++m) acc[m] = mfma16(A[m][4], asb(r0), acc[m]);
        #pragma unroll
        for (int m = 0; m < 4; ++m) acc[m] = mfma16(A[m][5], asb(r1), acc[m]);
        #pragma unroll
        for (int m = 0; m < 4; ++m) acc[m] = mfma16(A[m][6], asb(r2), acc[m]);
        #pragma unroll
        for (int m = 0; m < 4; ++m) acc[m] = mfma16(A[m][7], asb(r3), acc[m]);

        GSUM_WRITE(t & 1);
        __syncthreads();
        ACT_TAIL(ring + ((size_t)(t & 1)*4 + bg)*16384 + hg*512, (unsigned)(513 + t), (t & 1));
    }
#undef POLL
#undef GSUM_WRITE
#undef ACT_TAIL
}

// ---------------- final projection: out = h1_final @ lin_w.T + lin_b ----------------
__global__ void final_linear(const char* __restrict__ ws,
                             const float* __restrict__ linw, const float* __restrict__ linb,
                             float* __restrict__ out)
{
    __shared__ float hrow[512];
    int b = blockIdx.x;        // global batch 0..63
    int o = threadIdx.x;       // 64 outputs
    int bg = b >> 4, bl = b & 15;
    // t=511 -> ring parity 1; xch layout [par][bg][hg][b][p]
    const char* src = ws + OFF_RING + ((size_t)(4 + bg))*16384
                         + (o >> 1)*512 + bl*32 + (o & 1)*16;
    {
        us8v v = *(const us8v*)src;
        #pragma unroll
        for (int p = 0; p < 8; ++p)
            hrow[o*8+p] = __builtin_bit_cast(float, ((unsigned)v[p]) << 16);
    }
    __syncthreads();
    float acc = linb[o];
    const float* wrow = linw + o*512;
    #pragma unroll 8
    for (int k = 0; k < 512; ++k) acc += hrow[k] * wrow[k];
    out[b*64 + o] = acc;
}

extern "C" void kernel_launch(void* const* d_in, const int* in_sizes, int n_in,
                              void* d_out, int out_size, void* d_ws, size_t ws_size,
                              hipStream_t stream)
{
    const float* x    = (const float*)d_in[0];
    const float* wih0 = (const float*)d_in[1];
    const float* whh0 = (const float*)d_in[2];
    const float* bih0 = (const float*)d_in[3];
    const float* bhh0 = (const float*)d_in[4];
    const float* wih1 = (const float*)d_in[5];
    const float* whh1 = (const float*)d_in[6];
    const float* bih1 = (const float*)d_in[7];
    const float* bhh1 = (const float*)d_in[8];
    const float* linw = (const float*)d_in[9];
    const float* linb = (const float*)d_in[10];
    char* ws = (char*)d_ws;

    // zero epoch flags (visible to lstm_persist via dispatch-boundary ordering)
    (void)hipMemsetAsync(ws + OFF_FLAGS, 0, 16384, stream);
    hipLaunchKernelGGL(setup_kernel, dim3(1024), dim3(256), 0, stream,
                       x, wih0, whh0, bih0, bhh0, wih1, whh1, bih1, bhh1, ws);
    hipLaunchKernelGGL(lstm_persist, dim3(128), dim3(256), 0, stream, ws);
    hipLaunchKernelGGL(final_linear, dim3(64), dim3(64), 0, stream,
                       ws, linw, linb, (float*)d_out);
}